// Round 8
// baseline (740.345 us; speedup 1.0000x reference)
//
#include <hip/hip_runtime.h>
#include <hip/hip_bf16.h>
#include <math.h>

// KoLeo loss: dist_i = sqrt(2 - 2*max_{j!=i} <fhat_i, fhat_j>); loss = -mean(log(dist+1e-8))
// Row-max-of-Gram via MX-scaled fp8 MFMA (16x16x128 f8f6f4, unit scales, 4x4
// tiles/wave). R8: register-prefetch software pipeline — next K-tile is loaded to
// VGPRs during the MFMA phase and ds_written after the barrier, so the top-of-iter
// vmcnt(0) waits on ~550-cycle-old loads (latency hidden) while LDS stays single-
// buffered at 32KB (4 blocks/CU; R6's 64KB dbuf killed occupancy). Epilogue red/redc
// alias dead sA. Features pre-scaled x16 before e4m3 cast; raw dots carry x256,
// folded out in row_reduce (max monotone). Upper-triangle tiles; row+col max/tile.

#define N_ROWS 16384
#define DIM 1024     // elements per row == bytes per row in fp8
#define BT 128       // Gram tile edge
#define BKB 128      // K bytes staged per iteration (= one K=128 MFMA)
#define NT (N_ROWS / BT)

typedef int   i32x4 __attribute__((ext_vector_type(4)));
typedef int   i32x8 __attribute__((ext_vector_type(8)));
typedef float f32x4 __attribute__((ext_vector_type(4)));

// ---------------------------------------------------------------- normalize
__global__ __launch_bounds__(256) void normalize_kernel(
    const float* __restrict__ in, unsigned int* __restrict__ outp) {
  const int row = blockIdx.x;
  const int t = threadIdx.x;  // 256 threads x 4 floats
  const float4 v = ((const float4*)(in + (size_t)row * DIM))[t];
  float ss = v.x * v.x + v.y * v.y + v.z * v.z + v.w * v.w;
#pragma unroll
  for (int s = 1; s < 64; s <<= 1) ss += __shfl_xor(ss, s, 64);
  __shared__ float wsum[4];
  const int wave = t >> 6, lane = t & 63;
  if (lane == 0) wsum[wave] = ss;
  __syncthreads();
  const float tot = wsum[0] + wsum[1] + wsum[2] + wsum[3];
  const float scale = 16.f / fmaxf(sqrtf(tot), 1e-12f);
  unsigned int p = __builtin_amdgcn_cvt_pk_fp8_f32(v.x * scale, v.y * scale, 0, false);
  p = __builtin_amdgcn_cvt_pk_fp8_f32(v.z * scale, v.w * scale, p, true);
  outp[(size_t)row * (DIM / 4) + t] = p;
}

// -------------------------------------------------- Gram row/col-max GEMM
__global__ __launch_bounds__(256, 4) void gemm_rowmax(
    const unsigned char* __restrict__ F, float* __restrict__ partial) {
  const int jt = blockIdx.x, it = blockIdx.y;
  if (jt < it) return;  // lower triangle by symmetry

  __shared__ __align__(16) unsigned char sA[BT * BKB];  // 16KB, [row][k, swizzled]
  __shared__ __align__(16) unsigned char sB[BT * BKB];  // 16KB  (32KB total)

  const int ibase = it * BT, jbase = jt * BT;
  const int tid = threadIdx.x;
  const int wave = tid >> 6, lane = tid & 63;
  const int wi = wave >> 1, wj = wave & 1;  // 2x2 wave grid, 64x64 each
  const int quad = lane >> 4, r16 = lane & 15;

  // Per-thread staging geometry (loop-invariant): thread owns 4 granules/matrix.
  size_t gA[4], gB[4];
  int ldsoff[4];
#pragma unroll
  for (int q = 0; q < 4; ++q) {
    const int flat = q * 256 + wave * 64 + lane;  // physical granule = row*8 + k16
    const int row = flat >> 3;
    const int k16 = flat & 7;
    const int off = ((k16 ^ (row & 7)) << 4);  // XOR-swizzled logical granule
    gA[q] = (size_t)(ibase + row) * DIM + off;
    gB[q] = (size_t)(jbase + row) * DIM + off;
    ldsoff[q] = flat * 16;
  }

  f32x4 acc[4][4] = {};  // [mi][ni], 16x16 tiles (AGPR-resident)

  // Prefetch tile k0=0 into registers.
  i32x4 preA[4], preB[4];
#pragma unroll
  for (int q = 0; q < 4; ++q) {
    preA[q] = *(const i32x4*)(F + gA[q]);
    preB[q] = *(const i32x4*)(F + gB[q]);
  }

#pragma unroll 1
  for (int k0 = 0; k0 < DIM; k0 += BKB) {
    __syncthreads();  // closes prev iter's sA/sB reads; drains old prefetch vmcnt
#pragma unroll
    for (int q = 0; q < 4; ++q) {
      *(i32x4*)(sA + ldsoff[q]) = preA[q];
      *(i32x4*)(sB + ldsoff[q]) = preB[q];
    }
    __syncthreads();  // staging visible to all waves

    if (k0 + BKB < DIM) {  // prefetch next tile; flies behind the MFMA phase
#pragma unroll
      for (int q = 0; q < 4; ++q) {
        preA[q] = *(const i32x4*)(F + gA[q] + k0 + BKB);
        preB[q] = *(const i32x4*)(F + gB[q] + k0 + BKB);
      }
    }

    // A-frags: lane holds 32 contiguous logical k-bytes (granules 2q,2q+1) of row R
    i32x8 afr[4];
#pragma unroll
    for (int mi = 0; mi < 4; ++mi) {
      const int R = wi * 64 + mi * 16 + r16;
      const unsigned char* base = sA + R * BKB;
      i32x4 lo = *(const i32x4*)(base + (((2 * quad) ^ (R & 7)) << 4));
      i32x4 hi = *(const i32x4*)(base + (((2 * quad + 1) ^ (R & 7)) << 4));
      afr[mi] = __builtin_shufflevector(lo, hi, 0, 1, 2, 3, 4, 5, 6, 7);
    }
#pragma unroll
    for (int ni = 0; ni < 4; ++ni) {
      const int R = wj * 64 + ni * 16 + r16;
      const unsigned char* base = sB + R * BKB;
      i32x4 lo = *(const i32x4*)(base + (((2 * quad) ^ (R & 7)) << 4));
      i32x4 hi = *(const i32x4*)(base + (((2 * quad + 1) ^ (R & 7)) << 4));
      i32x8 bfr = __builtin_shufflevector(lo, hi, 0, 1, 2, 3, 4, 5, 6, 7);
#pragma unroll
      for (int mi = 0; mi < 4; ++mi)
        acc[mi][ni] = __builtin_amdgcn_mfma_scale_f32_16x16x128_f8f6f4(
            afr[mi], bfr, acc[mi][ni], 0, 0,  // cbsz=0 (fp8), blgp=0 (fp8)
            0, 0x7F7F7F7F, 0, 0x7F7F7F7F);    // unit e8m0 scales
    }
  }
  __syncthreads();  // all sA/sB reads done -> safe to alias epilogue scratch

  float(*red)[2] = (float(*)[2])(&sA[0]);          // [BT][2] row-max
  float(*redc)[2] = (float(*)[2])(&sA[0] + 1024);  // [BT][2] col-max

  // C/D layout (16x16): col = lane&15, row = quad*4 + reg.
#pragma unroll
  for (int mi = 0; mi < 4; ++mi) {
#pragma unroll
    for (int r = 0; r < 4; ++r) {
      const int rowg = ibase + wi * 64 + mi * 16 + quad * 4 + r;
      float m = -INFINITY;
#pragma unroll
      for (int ni = 0; ni < 4; ++ni) {
        const int colg = jbase + wj * 64 + ni * 16 + r16;
        const float v = acc[mi][ni][r];
        m = (rowg == colg) ? m : fmaxf(m, v);
      }
#pragma unroll
      for (int s = 1; s < 16; s <<= 1) m = fmaxf(m, __shfl_xor(m, s, 64));
      if (r16 == 0) red[wi * 64 + mi * 16 + quad * 4 + r][wj] = m;
    }
  }
  // Col-max (off-diagonal tiles: no diag elements present)
  if (it != jt) {
#pragma unroll
    for (int ni = 0; ni < 4; ++ni) {
      float m = -INFINITY;
#pragma unroll
      for (int mi = 0; mi < 4; ++mi)
#pragma unroll
        for (int r = 0; r < 4; ++r) m = fmaxf(m, acc[mi][ni][r]);
      m = fmaxf(m, __shfl_xor(m, 16, 64));  // reduce across quads
      m = fmaxf(m, __shfl_xor(m, 32, 64));
      if (quad == 0) redc[wj * 64 + ni * 16 + r16][wi] = m;
    }
  }
  __syncthreads();
  if (tid < BT) {
    partial[(size_t)jt * N_ROWS + ibase + tid] = fmaxf(red[tid][0], red[tid][1]);
  } else if (it != jt) {
    const int c = tid - BT;
    partial[(size_t)it * N_ROWS + jbase + c] = fmaxf(redc[c][0], redc[c][1]);
  }
}

// ------------------------------------------------------------- reductions
__global__ __launch_bounds__(256) void row_reduce(
    const float* __restrict__ partial, float* __restrict__ blocksum) {
  const int r = blockIdx.x * 256 + threadIdx.x;
  float m = -INFINITY;
  for (int p = 0; p < N_ROWS / BT; ++p)
    m = fmaxf(m, partial[(size_t)p * N_ROWS + r]);
  // raw dot carries x256 (features scaled x16): 2 - 2*(m/256) = 2 - m/128
  const float d2 = fmaxf(2.f - m * (1.f / 128.f), 0.f);
  float term = logf(sqrtf(d2) + 1e-8f);
#pragma unroll
  for (int s = 1; s < 64; s <<= 1) term += __shfl_xor(term, s, 64);
  __shared__ float wsum[4];
  const int wave = threadIdx.x >> 6, lane = threadIdx.x & 63;
  if (lane == 0) wsum[wave] = term;
  __syncthreads();
  if (threadIdx.x == 0)
    blocksum[blockIdx.x] = wsum[0] + wsum[1] + wsum[2] + wsum[3];
}

__global__ void finalize(const float* __restrict__ blocksum,
                         float* __restrict__ out) {
  float v = blocksum[threadIdx.x];
#pragma unroll
  for (int s = 1; s < 64; s <<= 1) v += __shfl_xor(v, s, 64);
  if (threadIdx.x == 0) out[0] = -v / (float)N_ROWS;
}

// ---------------------------------------------------------------- launcher
extern "C" void kernel_launch(void* const* d_in, const int* in_sizes, int n_in,
                              void* d_out, int out_size, void* d_ws, size_t ws_size,
                              hipStream_t stream) {
  const float* feats = (const float*)d_in[0];
  float* out = (float*)d_out;
  char* ws = (char*)d_ws;

  // ws: [0,16MB) fp8 features; [16MB,24MB) partial [128][16384] f32; then sums.
  unsigned char* f8 = (unsigned char*)ws;
  float* partial = (float*)(ws + (size_t)N_ROWS * DIM);
  float* blocksum =
      (float*)(ws + (size_t)N_ROWS * DIM + (size_t)NT * N_ROWS * 4);

  normalize_kernel<<<N_ROWS, 256, 0, stream>>>(feats, (unsigned int*)f8);
  gemm_rowmax<<<dim3(NT, NT), 256, 0, stream>>>(f8, partial);
  row_reduce<<<N_ROWS / 256, 256, 0, stream>>>(partial, blocksum);
  finalize<<<1, 64, 0, stream>>>(blocksum, out);
}

// Round 9
// 282.186 us; speedup vs baseline: 2.6236x; 2.6236x over previous
//
#include <hip/hip_runtime.h>
#include <hip/hip_bf16.h>
#include <math.h>

// KoLeo loss: dist_i = sqrt(2 - 2*max_{j!=i} <fhat_i, fhat_j>); loss = -mean(log(dist+1e-8))
// Row-max-of-Gram via MX-scaled fp8 MFMA (16x16x128 f8f6f4, unit scales, 4x4
// tiles/wave, single-buffered LDS, global_load_lds staging). R9 = R7 gemm verbatim
// (best measured: 210 us, MfmaUtil 28%, 4 blocks/CU) + exact triangular 1D grid
// (8256 blocks, R3-verified decode) instead of 2D early-exit.
// NOTE: at __launch_bounds__(256,4) the unified VGPR+AGPR budget is exactly
// 64+64=128 — ZERO headroom; R8's register prefetch spilled to scratch (2.2 GB HBM
// traffic, 3x regression). Do not add live state to the K-loop.
// Features pre-scaled x16 before e4m3 cast; raw dots carry x256, folded out in
// row_reduce (max is monotone). Each tile yields row-max AND col-max.

#define N_ROWS 16384
#define DIM 1024     // elements per row == bytes per row in fp8
#define BT 128       // Gram tile edge
#define BKB 128      // K bytes staged per iteration (= one K=128 MFMA)
#define NT (N_ROWS / BT)

typedef int   i32x4 __attribute__((ext_vector_type(4)));
typedef int   i32x8 __attribute__((ext_vector_type(8)));
typedef float f32x4 __attribute__((ext_vector_type(4)));

__device__ __forceinline__ void async16(const void* g, void* l) {
  __builtin_amdgcn_global_load_lds(
      (__attribute__((address_space(1))) const void*)g,
      (__attribute__((address_space(3))) void*)l, 16, 0, 0);
}

// ---------------------------------------------------------------- normalize
__global__ __launch_bounds__(256) void normalize_kernel(
    const float* __restrict__ in, unsigned int* __restrict__ outp) {
  const int row = blockIdx.x;
  const int t = threadIdx.x;  // 256 threads x 4 floats
  const float4 v = ((const float4*)(in + (size_t)row * DIM))[t];
  float ss = v.x * v.x + v.y * v.y + v.z * v.z + v.w * v.w;
#pragma unroll
  for (int s = 1; s < 64; s <<= 1) ss += __shfl_xor(ss, s, 64);
  __shared__ float wsum[4];
  const int wave = t >> 6, lane = t & 63;
  if (lane == 0) wsum[wave] = ss;
  __syncthreads();
  const float tot = wsum[0] + wsum[1] + wsum[2] + wsum[3];
  const float scale = 16.f / fmaxf(sqrtf(tot), 1e-12f);
  unsigned int p = __builtin_amdgcn_cvt_pk_fp8_f32(v.x * scale, v.y * scale, 0, false);
  p = __builtin_amdgcn_cvt_pk_fp8_f32(v.z * scale, v.w * scale, p, true);
  outp[(size_t)row * (DIM / 4) + t] = p;
}

// -------------------------------------------------- Gram row/col-max GEMM
__global__ __launch_bounds__(256, 4) void gemm_rowmax(
    const unsigned char* __restrict__ F, float* __restrict__ partial) {
  // triangular decode: bid -> (it, jt), it <= jt (verified exact in R3)
  const int bid = blockIdx.x;
  double disc = (double)(2 * NT + 1) * (2 * NT + 1) - 8.0 * (double)bid;
  int it = (int)(((2 * NT + 1) - sqrt(disc)) * 0.5);
  if (it > NT - 1) it = NT - 1;
  while (it > 0 && it * NT - it * (it - 1) / 2 > bid) --it;
  while ((it + 1) * NT - (it + 1) * it / 2 <= bid) ++it;
  const int jt = it + (bid - (it * NT - it * (it - 1) / 2));

  __shared__ __align__(16) unsigned char sA[BT * BKB];  // [row][k-byte, swizzled]
  __shared__ __align__(16) unsigned char sB[BT * BKB];
  __shared__ float red[BT][2];
  __shared__ float redc[BT][2];

  const int ibase = it * BT, jbase = jt * BT;
  const int tid = threadIdx.x;
  const int wave = tid >> 6, lane = tid & 63;
  const int wi = wave >> 1, wj = wave & 1;  // 2x2 wave grid, 64x64 each
  const int quad = lane >> 4, r16 = lane & 15;

  f32x4 acc[4][4] = {};  // [mi][ni], 16x16 tiles (AGPR-resident)

#pragma unroll 1
  for (int k0 = 0; k0 < DIM; k0 += BKB) {
    // stage A rows [ibase,+128) and B rows [jbase,+128): 8 granules/row,
    // physical slot p holds logical granule p ^ (row&7)
#pragma unroll
    for (int q = 0; q < 4; ++q) {
      const int flatb = q * 256 + wave * 64;  // wave-uniform granule base
      const int flat = flatb + lane;          // physical granule = row*8 + k16
      const int row = flat >> 3;
      const int k16 = flat & 7;
      const int off = ((k16 ^ (row & 7)) << 4);  // logical granule byte offset
      async16(F + (size_t)(ibase + row) * DIM + k0 + off,
              (char*)sA + (size_t)flatb * 16);
      async16(F + (size_t)(jbase + row) * DIM + k0 + off,
              (char*)sB + (size_t)flatb * 16);
    }
    __syncthreads();
    // A-frags: lane holds 32 contiguous k-bytes (granules 2q, 2q+1) of row R
    i32x8 afr[4];
#pragma unroll
    for (int mi = 0; mi < 4; ++mi) {
      const int R = wi * 64 + mi * 16 + r16;
      const unsigned char* base = sA + R * BKB;
      i32x4 lo = *(const i32x4*)(base + (((2 * quad) ^ (R & 7)) << 4));
      i32x4 hi = *(const i32x4*)(base + (((2 * quad + 1) ^ (R & 7)) << 4));
      afr[mi] = __builtin_shufflevector(lo, hi, 0, 1, 2, 3, 4, 5, 6, 7);
    }
#pragma unroll
    for (int ni = 0; ni < 4; ++ni) {
      const int R = wj * 64 + ni * 16 + r16;
      const unsigned char* base = sB + R * BKB;
      i32x4 lo = *(const i32x4*)(base + (((2 * quad) ^ (R & 7)) << 4));
      i32x4 hi = *(const i32x4*)(base + (((2 * quad + 1) ^ (R & 7)) << 4));
      i32x8 bfr = __builtin_shufflevector(lo, hi, 0, 1, 2, 3, 4, 5, 6, 7);
#pragma unroll
      for (int mi = 0; mi < 4; ++mi)
        acc[mi][ni] = __builtin_amdgcn_mfma_scale_f32_16x16x128_f8f6f4(
            afr[mi], bfr, acc[mi][ni], 0, 0,  // cbsz=0 (fp8), blgp=0 (fp8)
            0, 0x7F7F7F7F, 0, 0x7F7F7F7F);    // unit e8m0 scales
    }
    __syncthreads();
  }

  // C/D layout (16x16): col = lane&15, row = quad*4 + reg.
  // Row-max with diagonal mask (raw x256 dots; scale folded out later).
#pragma unroll
  for (int mi = 0; mi < 4; ++mi) {
#pragma unroll
    for (int r = 0; r < 4; ++r) {
      const int rowg = ibase + wi * 64 + mi * 16 + quad * 4 + r;
      float m = -INFINITY;
#pragma unroll
      for (int ni = 0; ni < 4; ++ni) {
        const int colg = jbase + wj * 64 + ni * 16 + r16;
        const float v = acc[mi][ni][r];
        m = (rowg == colg) ? m : fmaxf(m, v);
      }
#pragma unroll
      for (int s = 1; s < 16; s <<= 1) m = fmaxf(m, __shfl_xor(m, s, 64));
      if (r16 == 0) red[wi * 64 + mi * 16 + quad * 4 + r][wj] = m;
    }
  }
  // Col-max (off-diagonal tiles: no diag elements present)
  if (it != jt) {
#pragma unroll
    for (int ni = 0; ni < 4; ++ni) {
      float m = -INFINITY;
#pragma unroll
      for (int mi = 0; mi < 4; ++mi)
#pragma unroll
        for (int r = 0; r < 4; ++r) m = fmaxf(m, acc[mi][ni][r]);
      m = fmaxf(m, __shfl_xor(m, 16, 64));  // reduce across quads
      m = fmaxf(m, __shfl_xor(m, 32, 64));
      if (quad == 0) redc[wj * 64 + ni * 16 + r16][wi] = m;
    }
  }
  __syncthreads();
  if (tid < BT) {
    partial[(size_t)jt * N_ROWS + ibase + tid] = fmaxf(red[tid][0], red[tid][1]);
  } else if (it != jt) {
    const int c = tid - BT;
    partial[(size_t)it * N_ROWS + jbase + c] = fmaxf(redc[c][0], redc[c][1]);
  }
}

// ------------------------------------------------------------- reductions
__global__ __launch_bounds__(256) void row_reduce(
    const float* __restrict__ partial, float* __restrict__ blocksum) {
  const int r = blockIdx.x * 256 + threadIdx.x;
  float m = -INFINITY;
  for (int p = 0; p < N_ROWS / BT; ++p)
    m = fmaxf(m, partial[(size_t)p * N_ROWS + r]);
  // raw dot carries x256 (features scaled x16): 2 - 2*(m/256) = 2 - m/128
  const float d2 = fmaxf(2.f - m * (1.f / 128.f), 0.f);
  float term = logf(sqrtf(d2) + 1e-8f);
#pragma unroll
  for (int s = 1; s < 64; s <<= 1) term += __shfl_xor(term, s, 64);
  __shared__ float wsum[4];
  const int wave = threadIdx.x >> 6, lane = threadIdx.x & 63;
  if (lane == 0) wsum[wave] = term;
  __syncthreads();
  if (threadIdx.x == 0)
    blocksum[blockIdx.x] = wsum[0] + wsum[1] + wsum[2] + wsum[3];
}

__global__ void finalize(const float* __restrict__ blocksum,
                         float* __restrict__ out) {
  float v = blocksum[threadIdx.x];
#pragma unroll
  for (int s = 1; s < 64; s <<= 1) v += __shfl_xor(v, s, 64);
  if (threadIdx.x == 0) out[0] = -v / (float)N_ROWS;
}

// ---------------------------------------------------------------- launcher
extern "C" void kernel_launch(void* const* d_in, const int* in_sizes, int n_in,
                              void* d_out, int out_size, void* d_ws, size_t ws_size,
                              hipStream_t stream) {
  const float* feats = (const float*)d_in[0];
  float* out = (float*)d_out;
  char* ws = (char*)d_ws;

  // ws: [0,16MB) fp8 features; [16MB,24MB) partial [128][16384] f32; then sums.
  unsigned char* f8 = (unsigned char*)ws;
  float* partial = (float*)(ws + (size_t)N_ROWS * DIM);
  float* blocksum =
      (float*)(ws + (size_t)N_ROWS * DIM + (size_t)NT * N_ROWS * 4);

  normalize_kernel<<<N_ROWS, 256, 0, stream>>>(feats, (unsigned int*)f8);
  gemm_rowmax<<<NT * (NT + 1) / 2, 256, 0, stream>>>(f8, partial);
  row_reduce<<<N_ROWS / 256, 256, 0, stream>>>(partial, blocksum);
  finalize<<<1, 64, 0, stream>>>(blocksum, out);
}